// Round 2
// baseline (302.146 us; speedup 1.0000x reference)
//
#include <hip/hip_runtime.h>

// Problem constants
#define BB 4
#define NN 65536
#define CC 256
#define KK 4096
#define MIDC 128
#define SELCAP 81920   // per-batch candidate buffer (max total = 4095 + 65536)

// ---------------- Kernel Z: zero hist + cnt ----------------
__global__ __launch_bounds__(256) void zero_kernel(unsigned* __restrict__ p) {
    p[blockIdx.x * 256 + threadIdx.x] = 0u;
}

// ---------------- Kernel S: scores -> sortable keys + 16-bit histogram ----------------
__global__ __launch_bounds__(256) void score_kernel(const float* __restrict__ cls,
                                                    unsigned* __restrict__ keys,
                                                    unsigned* __restrict__ hist) {
    int i = blockIdx.x * 256 + threadIdx.x;          // 0 .. B*N-1
    float a = cls[i * 3 + 0];
    float b = cls[i * 3 + 1];
    float c = cls[i * 3 + 2];
    float s = fmaxf(fmaxf(a, b), c);
    unsigned u = __float_as_uint(s);
    u = (u & 0x80000000u) ? ~u : (u | 0x80000000u);  // order-preserving map
    keys[i] = u;
    int bat = i >> 16;                                // N == 65536
    atomicAdd(&hist[bat * 65536 + (u >> 16)], 1u);
}

// ---------------- Kernel T: per-batch threshold bin + rank bases ----------------
__global__ __launch_bounds__(1024) void thresh_kernel(const unsigned* __restrict__ hist,
                                                      unsigned* __restrict__ rankbase,
                                                      int* __restrict__ tinfo) {
    __shared__ unsigned ts[1024];
    int b = blockIdx.x;
    int t = threadIdx.x;
    const unsigned* hb = hist + b * 65536;
    unsigned* rb = rankbase + b * 65536;
    int base = t * 64;
    unsigned s = 0;
#pragma unroll
    for (int i = 0; i < 64; i++) s += hb[base + i];
    ts[t] = s;
    __syncthreads();
    // inclusive suffix scan over 1024 thread sums
    for (int off = 1; off < 1024; off <<= 1) {
        unsigned v = ts[t] + ((t + off) < 1024 ? ts[t + off] : 0u);
        __syncthreads();
        ts[t] = v;
        __syncthreads();
    }
    unsigned above = ts[t] - s;   // sum of all higher threads' bins
    // walk own bins from high to low
    for (int i = 63; i >= 0; i--) {
        unsigned h = hb[base + i];
        rb[base + i] = above;
        if ((int)above < KK && (int)(above + h) >= KK) {
            tinfo[b * 4 + 0] = base + i;            // threshold bin
            tinfo[b * 4 + 1] = KK - (int)above;     // krem
            tinfo[b * 4 + 2] = (int)(above + h);    // total candidates
        }
        above += h;
    }
}

// ---------------- Kernel C: collect candidates grouped by bin ----------------
__global__ __launch_bounds__(256) void collect_kernel(const unsigned* __restrict__ keys,
                                                      const unsigned* __restrict__ rankbase,
                                                      unsigned* __restrict__ cnt,
                                                      const int* __restrict__ tinfo,
                                                      unsigned long long* __restrict__ sel) {
    int i = blockIdx.x * 256 + threadIdx.x;   // 0 .. B*N-1
    int b = i >> 16;
    int n = i & 65535;
    unsigned u = keys[i];
    unsigned bin = u >> 16;
    if ((int)bin >= tinfo[b * 4 + 0]) {
        unsigned slot = rankbase[b * 65536 + bin] + atomicAdd(&cnt[b * 65536 + bin], 1u);
        sel[(size_t)b * SELCAP + slot] =
            ((unsigned long long)u << 32) | (unsigned)(~n);
    }
}

// ---------------- Kernel R: exact rank -> gather indices in top_k order ----------------
__global__ __launch_bounds__(256) void rank_kernel(const unsigned long long* __restrict__ sel,
                                                   const unsigned* __restrict__ rankbase,
                                                   const unsigned* __restrict__ cnt,
                                                   const int* __restrict__ tinfo,
                                                   int* __restrict__ idxout) {
    int b = blockIdx.y;
    int s = blockIdx.x * 256 + threadIdx.x;
    int total = tinfo[b * 4 + 2];
    if (s >= total) return;
    const unsigned long long* sb_ = sel + (size_t)b * SELCAP;
    unsigned long long key = sb_[s];
    unsigned bin = (unsigned)(key >> 48);
    unsigned base = rankbase[b * 65536 + bin];
    unsigned c = cnt[b * 65536 + bin];
    unsigned bigger = 0;
    for (unsigned j = 0; j < c; j++) bigger += (sb_[base + j] > key) ? 1u : 0u;
    unsigned pos = base + bigger;
    if (pos < KK) idxout[b * KK + pos] = (int)(~(unsigned)key);
}

// ---------------- Kernel B: gather + GEMM1 (C->MID) + BN partial stats + origins ----------------
#define KT 32
__global__ __launch_bounds__(256) void gemm1_kernel(const float* __restrict__ feats,
                                                    const float* __restrict__ points,
                                                    const float* __restrict__ w1,
                                                    const int* __restrict__ idx,
                                                    float* __restrict__ h_out,
                                                    float* __restrict__ psum,
                                                    float* __restrict__ psq,
                                                    float* __restrict__ outOrig) {
    __shared__ __align__(16) float w1s[MIDC][68];
    __shared__ __align__(16) float fs[KT][68];
    __shared__ int kidx[KT];
    __shared__ float redS[8][MIDC];
    __shared__ float redQ[8][MIDC];

    int t = threadIdx.x;
    int b = blockIdx.x >> 7;                 // K/KT = 128 tiles per batch
    int k0 = (blockIdx.x & 127) * KT;

    if (t < KT) kidx[t] = idx[b * KK + k0 + t];
    __syncthreads();

    if (t < KT * 3) {                        // gather origins (points)
        int k = t / 3, o = t % 3;
        outOrig[(size_t)(b * KK + k0 + k) * 3 + o] =
            points[((size_t)b * NN + kidx[k]) * 3 + o];
    }

    int tm = t & 31, tk = t >> 5;
    float acc[4][4] = {};

    for (int c0 = 0; c0 < CC; c0 += 64) {
        for (int e = t; e < MIDC * 64; e += 256) {      // stage w1 chunk
            int m = e >> 6, c = e & 63;
            w1s[m][c] = w1[m * CC + c0 + c];
        }
        for (int e = t; e < KT * 64; e += 256) {        // gather feats chunk (random columns)
            int k = e >> 6, c = e & 63;
            fs[k][c] = feats[((size_t)b * CC + c0 + c) * NN + kidx[k]];
        }
        __syncthreads();
#pragma unroll
        for (int c = 0; c < 64; c += 4) {
            float4 av[4], wv[4];
#pragma unroll
            for (int i = 0; i < 4; i++) av[i] = *reinterpret_cast<const float4*>(&fs[tk + 8 * i][c]);
#pragma unroll
            for (int j = 0; j < 4; j++) wv[j] = *reinterpret_cast<const float4*>(&w1s[tm + 32 * j][c]);
#pragma unroll
            for (int i = 0; i < 4; i++)
#pragma unroll
                for (int j = 0; j < 4; j++) {
                    acc[i][j] += av[i].x * wv[j].x;
                    acc[i][j] += av[i].y * wv[j].y;
                    acc[i][j] += av[i].z * wv[j].z;
                    acc[i][j] += av[i].w * wv[j].w;
                }
        }
        __syncthreads();
    }

    float ps[4] = {}, pq[4] = {};
#pragma unroll
    for (int i = 0; i < 4; i++) {
        int k = tk + 8 * i;
#pragma unroll
        for (int j = 0; j < 4; j++) {
            int m = tm + 32 * j;
            float v = acc[i][j];
            h_out[(size_t)(b * KK + k0 + k) * MIDC + m] = v;
            ps[j] += v;
            pq[j] += v * v;
        }
    }
#pragma unroll
    for (int j = 0; j < 4; j++) { redS[tk][tm + 32 * j] = ps[j]; redQ[tk][tm + 32 * j] = pq[j]; }
    __syncthreads();
    if (t < MIDC) {
        float s = 0.f, q = 0.f;
#pragma unroll
        for (int r = 0; r < 8; r++) { s += redS[r][t]; q += redQ[r][t]; }
        psum[blockIdx.x * MIDC + t] = s;
        psq[blockIdx.x * MIDC + t] = q;
    }
}

// ---------------- Kernel N: finalize BN stats -> scale/bias ----------------
__global__ __launch_bounds__(512) void bnstat_kernel(const float* __restrict__ psum,
                                                     const float* __restrict__ psq,
                                                     const float* __restrict__ gamma,
                                                     const float* __restrict__ beta,
                                                     float* __restrict__ sb) {
    __shared__ float rs[4][MIDC];
    __shared__ float rq[4][MIDC];
    int m = threadIdx.x & 127, g = threadIdx.x >> 7;
    float s = 0.f, q = 0.f;
    for (int blk = g; blk < 512; blk += 4) {
        s += psum[blk * MIDC + m];
        q += psq[blk * MIDC + m];
    }
    rs[g][m] = s; rq[g][m] = q;
    __syncthreads();
    if (threadIdx.x < MIDC) {
        float S = rs[0][m] + rs[1][m] + rs[2][m] + rs[3][m];
        float Q = rq[0][m] + rq[1][m] + rq[2][m] + rq[3][m];
        const float inv = 1.0f / (float)(BB * KK);
        float mean = S * inv;
        float var = Q * inv - mean * mean;
        float scale = gamma[m] * rsqrtf(var + 1e-5f);
        sb[m] = scale;
        sb[MIDC + m] = beta[m] - mean * scale;
    }
}

// ---------------- Kernel O: BN+ReLU+GEMM2(128->3)+clamp+add ----------------
__global__ __launch_bounds__(256) void out_kernel(const float* __restrict__ h,
                                                  const float* __restrict__ sb,
                                                  const float* __restrict__ w2,
                                                  const float* __restrict__ lim,
                                                  const float* __restrict__ orig,
                                                  float* __restrict__ preds,
                                                  float* __restrict__ offs) {
    int tid = blockIdx.x * 256 + threadIdx.x;
    int bk = tid >> 6;                // one wave per (b,k)
    int lane = tid & 63;
    const float* hp = h + (size_t)bk * MIDC;
    float h0 = hp[lane], h1 = hp[lane + 64];
    float y0 = fmaxf(h0 * sb[lane] + sb[MIDC + lane], 0.0f);
    float y1 = fmaxf(h1 * sb[lane + 64] + sb[MIDC + 64 + lane], 0.0f);
    float p0 = y0 * w2[lane]       + y1 * w2[lane + 64];
    float p1 = y0 * w2[128 + lane] + y1 * w2[192 + lane];
    float p2 = y0 * w2[256 + lane] + y1 * w2[320 + lane];
#pragma unroll
    for (int off = 32; off > 0; off >>= 1) {
        p0 += __shfl_xor(p0, off);
        p1 += __shfl_xor(p1, off);
        p2 += __shfl_xor(p2, off);
    }
    if (lane < 3) {
        float o = (lane == 0) ? p0 : ((lane == 1) ? p1 : p2);
        float L = lim[lane];
        float limited = fminf(fmaxf(o, -L), L);
        preds[bk * 3 + lane] = orig[bk * 3 + lane] + limited;
        offs[bk * 3 + lane] = o;
    }
}

// ---------------- launch ----------------
extern "C" void kernel_launch(void* const* d_in, const int* in_sizes, int n_in,
                              void* d_out, int out_size, void* d_ws, size_t ws_size,
                              hipStream_t stream) {
    const float* points   = (const float*)d_in[0];
    const float* features = (const float*)d_in[1];
    const float* cls      = (const float*)d_in[2];
    const float* w1       = (const float*)d_in[3];
    const float* gamma    = (const float*)d_in[4];
    const float* beta     = (const float*)d_in[5];
    const float* w2       = (const float*)d_in[6];
    const float* lim      = (const float*)d_in[7];

    float* out   = (float*)d_out;
    float* preds = out;                       // (B,K,3)
    float* orig  = out + BB * KK * 3;         // (B,K,3)
    float* offs  = out + 2 * BB * KK * 3;     // (B,K,3)

    char* ws = (char*)d_ws;
    unsigned long long* sel = (unsigned long long*)ws;                 // B*SELCAP u64
    size_t off = (size_t)BB * SELCAP * 8;
    unsigned* keys     = (unsigned*)(ws + off); off += (size_t)BB * NN * 4;
    unsigned* hist     = (unsigned*)(ws + off); off += (size_t)BB * 65536 * 4;
    unsigned* cnt      = (unsigned*)(ws + off); off += (size_t)BB * 65536 * 4;
    unsigned* rankbase = (unsigned*)(ws + off); off += (size_t)BB * 65536 * 4;
    int*      tinfo    = (int*)(ws + off);      off += 64;
    int*      idxw     = (int*)(ws + off);      off += (size_t)BB * KK * 4;
    float*    h        = (float*)(ws + off);    off += (size_t)BB * KK * MIDC * 4;
    float*    psum     = (float*)(ws + off);    off += (size_t)512 * MIDC * 4;
    float*    psq      = (float*)(ws + off);    off += (size_t)512 * MIDC * 4;
    float*    sb       = (float*)(ws + off);

    // zero hist+cnt (contiguous 2*B*65536 u32)
    zero_kernel<<<(2 * BB * 65536) / 256, 256, 0, stream>>>(hist);
    score_kernel<<<(BB * NN) / 256, 256, 0, stream>>>(cls, keys, hist);
    thresh_kernel<<<BB, 1024, 0, stream>>>(hist, rankbase, tinfo);
    collect_kernel<<<(BB * NN) / 256, 256, 0, stream>>>(keys, rankbase, cnt, tinfo, sel);
    {
        dim3 g(SELCAP / 256, BB);
        rank_kernel<<<g, 256, 0, stream>>>(sel, rankbase, cnt, tinfo, idxw);
    }
    gemm1_kernel<<<BB * (KK / KT), 256, 0, stream>>>(features, points, w1, idxw, h, psum, psq, orig);
    bnstat_kernel<<<1, 512, 0, stream>>>(psum, psq, gamma, beta, sb);
    out_kernel<<<(BB * KK * 64) / 256, 256, 0, stream>>>(h, sb, w2, lim, orig, preds, offs);
}

// Round 3
// 263.202 us; speedup vs baseline: 1.1480x; 1.1480x over previous
//
#include <hip/hip_runtime.h>

// Problem constants
#define BB 4
#define NN 65536
#define CC 256
#define KK 4096
#define MIDC 128

// ============ Kernel 1: fused score + exact top-K per batch, all in LDS ============
// 13-bit bins (sign+exp+4 mantissa bits of the order-preserving key map).
// Composite key64 = (key32<<32)|~n : all distinct; descending key64 order ==
// descending score with ascending-index tie-break (jax.lax.top_k semantics).
#define BINS 8192
#define SELC 8192
__global__ __launch_bounds__(1024) void select_kernel(const float* __restrict__ cls,
                                                      int* __restrict__ idxout) {
    __shared__ unsigned hist[BINS];            // becomes rankbase in-place
    __shared__ unsigned cnt[BINS];
    __shared__ unsigned long long sel[SELC];
    __shared__ unsigned ts[1024];
    __shared__ int tinfo[2];                   // {threshold bin, total candidates}

    int b = blockIdx.x;
    int t = threadIdx.x;
    const float* cb = cls + (size_t)b * NN * 3;

    for (int i = t; i < BINS; i += 1024) { hist[i] = 0u; cnt[i] = 0u; }
    __syncthreads();

    // P1: compute keys, build histogram
    for (int n = t; n < NN; n += 1024) {
        float a = cb[n * 3], x = cb[n * 3 + 1], y = cb[n * 3 + 2];
        float s = fmaxf(fmaxf(a, x), y);
        unsigned u = __float_as_uint(s);
        u = (u & 0x80000000u) ? ~u : (u | 0x80000000u);
        atomicAdd(&hist[u >> 19], 1u);
    }
    __syncthreads();

    // P2: suffix scan (8 contiguous bins per thread) -> rankbase + threshold
    int base = t * 8;
    unsigned hloc[8];
    unsigned s8 = 0;
#pragma unroll
    for (int i = 0; i < 8; i++) { hloc[i] = hist[base + i]; s8 += hloc[i]; }
    ts[t] = s8;
    __syncthreads();
    for (int off = 1; off < 1024; off <<= 1) {
        unsigned v = ts[t] + ((t + off) < 1024 ? ts[t + off] : 0u);
        __syncthreads();
        ts[t] = v;
        __syncthreads();
    }
    unsigned above = ts[t] - s8;               // keys in bins owned by threads > t
#pragma unroll
    for (int i = 7; i >= 0; i--) {
        unsigned h = hloc[i];
        hist[base + i] = above;                // rankbase (in-place overwrite)
        if ((int)above < KK && (int)(above + h) >= KK) {
            tinfo[0] = base + i;
            tinfo[1] = (int)(above + h);
        }
        above += h;
    }
    __syncthreads();
    int tbin = tinfo[0];

    // P3: recompute keys, compact candidates grouped by bin
    for (int n = t; n < NN; n += 1024) {
        float a = cb[n * 3], x = cb[n * 3 + 1], y = cb[n * 3 + 2];
        float s = fmaxf(fmaxf(a, x), y);
        unsigned u = __float_as_uint(s);
        u = (u & 0x80000000u) ? ~u : (u | 0x80000000u);
        int bin = (int)(u >> 19);
        if (bin >= tbin) {
            unsigned slot = hist[bin] + atomicAdd(&cnt[bin], 1u);
            if (slot < SELC)
                sel[slot] = ((unsigned long long)u << 32) | (unsigned)(~n);
        }
    }
    __syncthreads();

    // P4: exact rank within bin -> emit in top_k order
    int total = min(tinfo[1], SELC);
    for (int s_ = t; s_ < total; s_ += 1024) {
        unsigned long long key = sel[s_];
        int bin = (int)(key >> 51);
        unsigned sbase = hist[bin];
        unsigned c = min(cnt[bin], (unsigned)SELC - sbase);
        unsigned bigger = 0;
        for (unsigned j = 0; j < c; j++) bigger += (sel[sbase + j] > key) ? 1u : 0u;
        unsigned pos = sbase + bigger;
        if (pos < KK) idxout[b * KK + pos] = (int)(~(unsigned)key);
    }
}

// ============ Kernel 2: gather + GEMM1 (C->MID) + BN partials + origins ============
#define KT 64
__global__ __launch_bounds__(256) void gemm1_kernel(const float* __restrict__ feats,
                                                    const float* __restrict__ points,
                                                    const float* __restrict__ w1,
                                                    const int* __restrict__ idx,
                                                    float* __restrict__ h_out,
                                                    float* __restrict__ psum,
                                                    float* __restrict__ psq,
                                                    float* __restrict__ outOrig) {
    __shared__ __align__(16) float w1s[MIDC][68];   // 34.8 KB
    __shared__ __align__(16) float fs[KT][68];      // 17.4 KB
    __shared__ int kidx[KT];
    __shared__ float redS[16][MIDC];                // 8 KB
    __shared__ float redQ[16][MIDC];                // 8 KB

    int t = threadIdx.x;
    int b = blockIdx.x >> 6;                  // K/KT = 64 tiles per batch
    int k0 = (blockIdx.x & 63) * KT;

    if (t < KT) kidx[t] = idx[b * KK + k0 + t];
    __syncthreads();

    if (t < KT * 3) {                         // gather origins
        int k = t / 3, o = t % 3;
        outOrig[(size_t)(b * KK + k0 + k) * 3 + o] =
            points[((size_t)b * NN + kidx[k]) * 3 + o];
    }

    int tm = t & 15;        // 16 m-groups
    int tk = t >> 4;        // 16 k-groups
    float acc[4][8] = {};

    for (int c0 = 0; c0 < CC; c0 += 64) {
        for (int e = t; e < MIDC * 64; e += 256) {       // stage w1 chunk (coalesced)
            int m = e >> 6, c = e & 63;
            w1s[m][c] = w1[m * CC + c0 + c];
        }
        for (int e = t; e < KT * 64; e += 256) {         // gather feats: lanes -> consecutive k
            int k = e & 63, c = e >> 6;                  // (same feature row per wave-half)
            fs[k][c] = feats[((size_t)b * CC + c0 + c) * NN + kidx[k]];
        }
        __syncthreads();
#pragma unroll
        for (int c = 0; c < 64; c += 4) {
            float4 av[4], wv[8];
#pragma unroll
            for (int i = 0; i < 4; i++) av[i] = *reinterpret_cast<const float4*>(&fs[tk + 16 * i][c]);
#pragma unroll
            for (int j = 0; j < 8; j++) wv[j] = *reinterpret_cast<const float4*>(&w1s[tm + 16 * j][c]);
#pragma unroll
            for (int i = 0; i < 4; i++)
#pragma unroll
                for (int j = 0; j < 8; j++) {
                    acc[i][j] += av[i].x * wv[j].x;
                    acc[i][j] += av[i].y * wv[j].y;
                    acc[i][j] += av[i].z * wv[j].z;
                    acc[i][j] += av[i].w * wv[j].w;
                }
        }
        __syncthreads();
    }

    // write h + per-thread BN partials
    float ps[8] = {}, pq[8] = {};
#pragma unroll
    for (int i = 0; i < 4; i++) {
        int k = tk + 16 * i;
#pragma unroll
        for (int j = 0; j < 8; j++) {
            int m = tm + 16 * j;
            float v = acc[i][j];
            h_out[(size_t)(b * KK + k0 + k) * MIDC + m] = v;
            ps[j] += v;
            pq[j] += v * v;
        }
    }
#pragma unroll
    for (int j = 0; j < 8; j++) { redS[tk][tm + 16 * j] = ps[j]; redQ[tk][tm + 16 * j] = pq[j]; }
    __syncthreads();
    if (t < MIDC) {
        float s = 0.f, q = 0.f;
#pragma unroll
        for (int r = 0; r < 16; r++) { s += redS[r][t]; q += redQ[r][t]; }
        psum[blockIdx.x * MIDC + t] = s;
        psq[blockIdx.x * MIDC + t] = q;
    }
}

// ============ Kernel 3: finalize BN stats -> scale/bias ============
__global__ __launch_bounds__(512) void bnstat_kernel(const float* __restrict__ psum,
                                                     const float* __restrict__ psq,
                                                     const float* __restrict__ gamma,
                                                     const float* __restrict__ beta,
                                                     float* __restrict__ sb) {
    __shared__ float rs[4][MIDC];
    __shared__ float rq[4][MIDC];
    int m = threadIdx.x & 127, g = threadIdx.x >> 7;
    float s = 0.f, q = 0.f;
    for (int blk = g; blk < 256; blk += 4) {
        s += psum[blk * MIDC + m];
        q += psq[blk * MIDC + m];
    }
    rs[g][m] = s; rq[g][m] = q;
    __syncthreads();
    if (threadIdx.x < MIDC) {
        float S = rs[0][m] + rs[1][m] + rs[2][m] + rs[3][m];
        float Q = rq[0][m] + rq[1][m] + rq[2][m] + rq[3][m];
        const float inv = 1.0f / (float)(BB * KK);
        float mean = S * inv;
        float var = Q * inv - mean * mean;
        float scale = gamma[m] * rsqrtf(var + 1e-5f);
        sb[m] = scale;
        sb[MIDC + m] = beta[m] - mean * scale;
    }
}

// ============ Kernel 4: BN+ReLU+GEMM2(128->3)+clamp+add ============
__global__ __launch_bounds__(256) void out_kernel(const float* __restrict__ h,
                                                  const float* __restrict__ sb,
                                                  const float* __restrict__ w2,
                                                  const float* __restrict__ lim,
                                                  const float* __restrict__ orig,
                                                  float* __restrict__ preds,
                                                  float* __restrict__ offs) {
    int tid = blockIdx.x * 256 + threadIdx.x;
    int bk = tid >> 6;                // one wave per (b,k)
    int lane = tid & 63;
    const float* hp = h + (size_t)bk * MIDC;
    float h0 = hp[lane], h1 = hp[lane + 64];
    float y0 = fmaxf(h0 * sb[lane] + sb[MIDC + lane], 0.0f);
    float y1 = fmaxf(h1 * sb[lane + 64] + sb[MIDC + 64 + lane], 0.0f);
    float p0 = y0 * w2[lane]       + y1 * w2[lane + 64];
    float p1 = y0 * w2[128 + lane] + y1 * w2[192 + lane];
    float p2 = y0 * w2[256 + lane] + y1 * w2[320 + lane];
#pragma unroll
    for (int off = 32; off > 0; off >>= 1) {
        p0 += __shfl_xor(p0, off);
        p1 += __shfl_xor(p1, off);
        p2 += __shfl_xor(p2, off);
    }
    if (lane < 3) {
        float o = (lane == 0) ? p0 : ((lane == 1) ? p1 : p2);
        float L = lim[lane];
        float limited = fminf(fmaxf(o, -L), L);
        preds[bk * 3 + lane] = orig[bk * 3 + lane] + limited;
        offs[bk * 3 + lane] = o;
    }
}

// ============ launch ============
extern "C" void kernel_launch(void* const* d_in, const int* in_sizes, int n_in,
                              void* d_out, int out_size, void* d_ws, size_t ws_size,
                              hipStream_t stream) {
    const float* points   = (const float*)d_in[0];
    const float* features = (const float*)d_in[1];
    const float* cls      = (const float*)d_in[2];
    const float* w1       = (const float*)d_in[3];
    const float* gamma    = (const float*)d_in[4];
    const float* beta     = (const float*)d_in[5];
    const float* w2       = (const float*)d_in[6];
    const float* lim      = (const float*)d_in[7];

    float* out   = (float*)d_out;
    float* preds = out;                       // (B,K,3)
    float* orig  = out + BB * KK * 3;         // (B,K,3)
    float* offs  = out + 2 * BB * KK * 3;     // (B,K,3)

    float* wsf = (float*)d_ws;
    int*   idxw = (int*)wsf;                               // B*K
    float* h    = wsf + BB * KK;                           // B*K*MID
    float* psum = h + (size_t)BB * KK * MIDC;              // 256*MID
    float* psq  = psum + 256 * MIDC;                       // 256*MID
    float* sb   = psq + 256 * MIDC;                        // 2*MID

    select_kernel<<<BB, 1024, 0, stream>>>(cls, idxw);
    gemm1_kernel<<<BB * (KK / KT), 256, 0, stream>>>(features, points, w1, idxw, h, psum, psq, orig);
    bnstat_kernel<<<1, 512, 0, stream>>>(psum, psq, gamma, beta, sb);
    out_kernel<<<(BB * KK * 64) / 256, 256, 0, stream>>>(h, sb, w2, lim, orig, preds, offs);
}

// Round 4
// 205.155 us; speedup vs baseline: 1.4728x; 1.2829x over previous
//
#include <hip/hip_runtime.h>

// Problem constants
#define BB 4
#define NN 65536
#define CC 256
#define KK 4096
#define MIDC 128

// ============ Kernel 1: fused score + exact top-K per batch, all in LDS ============
// 13-bit bins (sign+exp+4 mantissa bits of the order-preserving key map) find the
// threshold bin; candidates (bin >= tbin, ~5-6K of them) are compacted into LDS and
// bitonic-sorted as composite key64 = (key32<<32)|~n (all distinct; descending key64
// == descending score, ascending index on ties == jax.lax.top_k order).
#define BINS 8192
#define SELC 8192
__global__ __launch_bounds__(1024) void select_kernel(const float* __restrict__ cls,
                                                      int* __restrict__ idxout) {
    __shared__ unsigned hist[BINS];
    __shared__ unsigned long long sel[SELC];
    __shared__ unsigned ts[1024];
    __shared__ int tinfo[1];
    __shared__ unsigned scnt;

    int b = blockIdx.x;
    int t = threadIdx.x;
    const float4* cb4 = reinterpret_cast<const float4*>(cls + (size_t)b * NN * 3);

    for (int i = t; i < BINS; i += 1024) hist[i] = 0u;
    if (t == 0) scnt = 0u;
    __syncthreads();

    // P1: keys (4 points per thread per iter, float4 loads) -> histogram
    for (int it = 0; it < 16; ++it) {
        int fb = it * 3072 + t * 3;
        float4 v0 = cb4[fb], v1 = cb4[fb + 1], v2 = cb4[fb + 2];
        float m[4];
        m[0] = fmaxf(fmaxf(v0.x, v0.y), v0.z);
        m[1] = fmaxf(fmaxf(v0.w, v1.x), v1.y);
        m[2] = fmaxf(fmaxf(v1.z, v1.w), v2.x);
        m[3] = fmaxf(fmaxf(v2.y, v2.z), v2.w);
#pragma unroll
        for (int j = 0; j < 4; j++) {
            unsigned u = __float_as_uint(m[j]);
            u = (u & 0x80000000u) ? ~u : (u | 0x80000000u);
            atomicAdd(&hist[u >> 19], 1u);
        }
    }
    __syncthreads();

    // P2: suffix scan over 8 contiguous bins/thread -> threshold bin
    int base = t * 8;
    unsigned hloc[8];
    unsigned s8 = 0;
#pragma unroll
    for (int i = 0; i < 8; i++) { hloc[i] = hist[base + i]; s8 += hloc[i]; }
    ts[t] = s8;
    __syncthreads();
    for (int off = 1; off < 1024; off <<= 1) {
        unsigned v = ts[t] + ((t + off) < 1024 ? ts[t + off] : 0u);
        __syncthreads();
        ts[t] = v;
        __syncthreads();
    }
    unsigned above = ts[t] - s8;               // keys in bins owned by threads > t
#pragma unroll
    for (int i = 7; i >= 0; i--) {
        unsigned h = hloc[i];
        if ((int)above < KK && (int)(above + h) >= KK) tinfo[0] = base + i;
        above += h;
    }
    for (int i = t; i < SELC; i += 1024) sel[i] = 0ull;   // pad value (< any real key)
    __syncthreads();
    int tbin = tinfo[0];

    // P3: recompute keys, ballot-aggregated compaction of candidates
    int lane = t & 63;
    for (int it = 0; it < 16; ++it) {
        int fb = it * 3072 + t * 3;
        float4 v0 = cb4[fb], v1 = cb4[fb + 1], v2 = cb4[fb + 2];
        float m[4];
        m[0] = fmaxf(fmaxf(v0.x, v0.y), v0.z);
        m[1] = fmaxf(fmaxf(v0.w, v1.x), v1.y);
        m[2] = fmaxf(fmaxf(v1.z, v1.w), v2.x);
        m[3] = fmaxf(fmaxf(v2.y, v2.z), v2.w);
#pragma unroll
        for (int j = 0; j < 4; j++) {
            unsigned u = __float_as_uint(m[j]);
            u = (u & 0x80000000u) ? ~u : (u | 0x80000000u);
            bool flag = (int)(u >> 19) >= tbin;
            unsigned long long mask = __ballot(flag);
            if (mask) {
                int leader = __ffsll((long long)mask) - 1;
                unsigned wbase = 0;
                if (lane == leader) wbase = atomicAdd(&scnt, (unsigned)__popcll(mask));
                wbase = __shfl(wbase, leader);
                if (flag) {
                    int n = it * 4096 + t * 4 + j;
                    unsigned pos = wbase + (unsigned)__popcll(mask & ((1ull << lane) - 1ull));
                    if (pos < SELC)
                        sel[pos] = ((unsigned long long)u << 32) | (unsigned)(~n);
                }
            }
        }
    }
    __syncthreads();

    // P4: bitonic sort ascending (pads at bottom), 4 pairs/thread/stage
    for (unsigned size = 2; size <= SELC; size <<= 1) {
        for (unsigned stride = size >> 1; stride > 0; stride >>= 1) {
            __syncthreads();
#pragma unroll 4
            for (unsigned p = t; p < SELC / 2; p += 1024) {
                unsigned lo = p & (stride - 1);
                unsigned i = ((p ^ lo) << 1) | lo;
                unsigned jj = i + stride;
                bool asc = ((i & size) == 0);
                unsigned long long a = sel[i], c = sel[jj];
                if ((a > c) == asc) { sel[i] = c; sel[jj] = a; }
            }
        }
    }
    __syncthreads();

    // emit: k-th largest = sel[SELC-1-k]
    for (int k = t; k < KK; k += 1024) {
        unsigned long long key = sel[SELC - 1 - k];
        idxout[b * KK + k] = (int)(~(unsigned)key);
    }
}

// ============ Kernel 2: gather + GEMM1 (C->MID) + BN partials + origins ============
#define KT 64
__global__ __launch_bounds__(256) void gemm1_kernel(const float* __restrict__ feats,
                                                    const float* __restrict__ points,
                                                    const float* __restrict__ w1,
                                                    const int* __restrict__ idx,
                                                    float* __restrict__ h_out,
                                                    float* __restrict__ psum,
                                                    float* __restrict__ psq,
                                                    float* __restrict__ outOrig) {
    __shared__ __align__(16) float w1s[MIDC][68];   // 34.8 KB
    __shared__ __align__(16) float fs[KT][68];      // 17.4 KB
    __shared__ int kidx[KT];
    __shared__ float redS[16][MIDC];                // 8 KB
    __shared__ float redQ[16][MIDC];                // 8 KB

    int t = threadIdx.x;
    int b = blockIdx.x >> 6;                  // K/KT = 64 tiles per batch
    int k0 = (blockIdx.x & 63) * KT;

    if (t < KT) kidx[t] = idx[b * KK + k0 + t];
    __syncthreads();

    if (t < KT * 3) {                         // gather origins
        int k = t / 3, o = t % 3;
        outOrig[(size_t)(b * KK + k0 + k) * 3 + o] =
            points[((size_t)b * NN + kidx[k]) * 3 + o];
    }

    int tm = t & 15;        // 16 m-groups
    int tk = t >> 4;        // 16 k-groups
    float acc[4][8] = {};

    for (int c0 = 0; c0 < CC; c0 += 64) {
        for (int e = t; e < MIDC * 64; e += 256) {       // stage w1 chunk (coalesced)
            int m = e >> 6, c = e & 63;
            w1s[m][c] = w1[m * CC + c0 + c];
        }
        for (int e = t; e < KT * 64; e += 256) {         // gather feats: lanes -> consecutive k
            int k = e & 63, c = e >> 6;
            fs[k][c] = feats[((size_t)b * CC + c0 + c) * NN + kidx[k]];
        }
        __syncthreads();
#pragma unroll
        for (int c = 0; c < 64; c += 4) {
            float4 av[4], wv[8];
#pragma unroll
            for (int i = 0; i < 4; i++) av[i] = *reinterpret_cast<const float4*>(&fs[tk + 16 * i][c]);
#pragma unroll
            for (int j = 0; j < 8; j++) wv[j] = *reinterpret_cast<const float4*>(&w1s[tm + 16 * j][c]);
#pragma unroll
            for (int i = 0; i < 4; i++)
#pragma unroll
                for (int j = 0; j < 8; j++) {
                    acc[i][j] += av[i].x * wv[j].x;
                    acc[i][j] += av[i].y * wv[j].y;
                    acc[i][j] += av[i].z * wv[j].z;
                    acc[i][j] += av[i].w * wv[j].w;
                }
        }
        __syncthreads();
    }

    // write h + per-thread BN partials
    float ps[8] = {}, pq[8] = {};
#pragma unroll
    for (int i = 0; i < 4; i++) {
        int k = tk + 16 * i;
#pragma unroll
        for (int j = 0; j < 8; j++) {
            int m = tm + 16 * j;
            float v = acc[i][j];
            h_out[(size_t)(b * KK + k0 + k) * MIDC + m] = v;
            ps[j] += v;
            pq[j] += v * v;
        }
    }
#pragma unroll
    for (int j = 0; j < 8; j++) { redS[tk][tm + 16 * j] = ps[j]; redQ[tk][tm + 16 * j] = pq[j]; }
    __syncthreads();
    if (t < MIDC) {
        float s = 0.f, q = 0.f;
#pragma unroll
        for (int r = 0; r < 16; r++) { s += redS[r][t]; q += redQ[r][t]; }
        psum[blockIdx.x * MIDC + t] = s;
        psq[blockIdx.x * MIDC + t] = q;
    }
}

// ============ Kernel 3: finalize BN stats -> scale/bias ============
__global__ __launch_bounds__(512) void bnstat_kernel(const float* __restrict__ psum,
                                                     const float* __restrict__ psq,
                                                     const float* __restrict__ gamma,
                                                     const float* __restrict__ beta,
                                                     float* __restrict__ sb) {
    __shared__ float rs[4][MIDC];
    __shared__ float rq[4][MIDC];
    int m = threadIdx.x & 127, g = threadIdx.x >> 7;
    float s = 0.f, q = 0.f;
    for (int blk = g; blk < 256; blk += 4) {
        s += psum[blk * MIDC + m];
        q += psq[blk * MIDC + m];
    }
    rs[g][m] = s; rq[g][m] = q;
    __syncthreads();
    if (threadIdx.x < MIDC) {
        float S = rs[0][m] + rs[1][m] + rs[2][m] + rs[3][m];
        float Q = rq[0][m] + rq[1][m] + rq[2][m] + rq[3][m];
        const float inv = 1.0f / (float)(BB * KK);
        float mean = S * inv;
        float var = Q * inv - mean * mean;
        float scale = gamma[m] * rsqrtf(var + 1e-5f);
        sb[m] = scale;
        sb[MIDC + m] = beta[m] - mean * scale;
    }
}

// ============ Kernel 4: BN+ReLU+GEMM2(128->3)+clamp+add ============
__global__ __launch_bounds__(256) void out_kernel(const float* __restrict__ h,
                                                  const float* __restrict__ sb,
                                                  const float* __restrict__ w2,
                                                  const float* __restrict__ lim,
                                                  const float* __restrict__ orig,
                                                  float* __restrict__ preds,
                                                  float* __restrict__ offs) {
    int tid = blockIdx.x * 256 + threadIdx.x;
    int bk = tid >> 6;                // one wave per (b,k)
    int lane = tid & 63;
    const float* hp = h + (size_t)bk * MIDC;
    float h0 = hp[lane], h1 = hp[lane + 64];
    float y0 = fmaxf(h0 * sb[lane] + sb[MIDC + lane], 0.0f);
    float y1 = fmaxf(h1 * sb[lane + 64] + sb[MIDC + 64 + lane], 0.0f);
    float p0 = y0 * w2[lane]       + y1 * w2[lane + 64];
    float p1 = y0 * w2[128 + lane] + y1 * w2[192 + lane];
    float p2 = y0 * w2[256 + lane] + y1 * w2[320 + lane];
#pragma unroll
    for (int off = 32; off > 0; off >>= 1) {
        p0 += __shfl_xor(p0, off);
        p1 += __shfl_xor(p1, off);
        p2 += __shfl_xor(p2, off);
    }
    if (lane < 3) {
        float o = (lane == 0) ? p0 : ((lane == 1) ? p1 : p2);
        float L = lim[lane];
        float limited = fminf(fmaxf(o, -L), L);
        preds[bk * 3 + lane] = orig[bk * 3 + lane] + limited;
        offs[bk * 3 + lane] = o;
    }
}

// ============ launch ============
extern "C" void kernel_launch(void* const* d_in, const int* in_sizes, int n_in,
                              void* d_out, int out_size, void* d_ws, size_t ws_size,
                              hipStream_t stream) {
    const float* points   = (const float*)d_in[0];
    const float* features = (const float*)d_in[1];
    const float* cls      = (const float*)d_in[2];
    const float* w1       = (const float*)d_in[3];
    const float* gamma    = (const float*)d_in[4];
    const float* beta     = (const float*)d_in[5];
    const float* w2       = (const float*)d_in[6];
    const float* lim      = (const float*)d_in[7];

    float* out   = (float*)d_out;
    float* preds = out;                       // (B,K,3)
    float* orig  = out + BB * KK * 3;         // (B,K,3)
    float* offs  = out + 2 * BB * KK * 3;     // (B,K,3)

    float* wsf = (float*)d_ws;
    int*   idxw = (int*)wsf;                               // B*K
    float* h    = wsf + BB * KK;                           // B*K*MID
    float* psum = h + (size_t)BB * KK * MIDC;              // 256*MID
    float* psq  = psum + 256 * MIDC;                       // 256*MID
    float* sb   = psq + 256 * MIDC;                        // 2*MID

    select_kernel<<<BB, 1024, 0, stream>>>(cls, idxw);
    gemm1_kernel<<<BB * (KK / KT), 256, 0, stream>>>(features, points, w1, idxw, h, psum, psq, orig);
    bnstat_kernel<<<1, 512, 0, stream>>>(psum, psq, gamma, beta, sb);
    out_kernel<<<(BB * KK * 64) / 256, 256, 0, stream>>>(h, sb, w2, lim, orig, preds, offs);
}